// Round 9
// baseline (158.395 us; speedup 1.0000x reference)
//
#include <hip/hip_runtime.h>
#include <hip/hip_bf16.h>
#include <math.h>

#define BB 256
#define TT 4096

typedef float f4 __attribute__((ext_vector_type(4)));

typedef const __attribute__((address_space(1))) void* as1_t;
typedef __attribute__((address_space(3))) void* as3_t;

__device__ __forceinline__ void gl_lds16(const float* g, const float* l) {
    // async global->LDS DMA: 16B per active lane; LDS dest = uniform base +
    // lane*16 (contiguous); global src per-lane.
    __builtin_amdgcn_global_load_lds((as1_t)g, (as3_t)l, 16, 0, 0);
}

// Cumulative feature offsets per k segment (k=2..10)
__constant__ int SEGF[10] = {0, 3, 9, 19, 34, 55, 83, 119, 164, 219};

// softmax + packed upper-triangle outer-product accumulate (static idx only)
template <int K>
__device__ __forceinline__ void row_update(float (&v)[K],
                                           float (&acc)[K * (K + 1) / 2]) {
    float m = v[0];
#pragma unroll
    for (int c = 1; c < K; ++c) m = fmaxf(m, v[c]);
    float s = 0.f;
#pragma unroll
    for (int c = 0; c < K; ++c) { v[c] = __expf(v[c] - m); s += v[c]; }
    const float inv = 1.0f / s;
#pragma unroll
    for (int c = 0; c < K; ++c) v[c] *= inv;
    int idx = 0;
#pragma unroll
    for (int i = 0; i < K; ++i) {
#pragma unroll
        for (int j = i; j < K; ++j) {
            acc[idx] = fmaf(v[i], v[j], acc[idx]);
            ++idx;
        }
    }
}

// ---------------------------------------------------------------------------
// Per-k kernel: grid = 512 blocks = (b, ch); chunk = 2048 rows; wave w owns
// rows [512w, 512w+512) of the chunk as 8 tiles x 64 rows.
// QUAD-buffered global_load_lds pipeline, depth-3 prefetch: tiles t..t+3 in
// flight (up to 3*VOPS outstanding load-instrs ~ 7.5KB/wave), counted vmcnt
// (never 0 until the tail). No __syncthreads in the main loop (wave-private
// buffers). Epilogue identical to the R4/R7-proven version.
// ---------------------------------------------------------------------------
template <int K>
__global__ __launch_bounds__(256, 2) void gk(const float* __restrict__ L,
                                             float* __restrict__ ws) {
    constexpr int NACC = K * (K + 1) / 2;
    constexpr int VF = K / 4;            // full 1KB gl_lds ops per tile
    constexpr int RL = 16 * (K % 4);     // remainder active lanes
    constexpr int VOPS = VF + (RL ? 1 : 0);
    constexpr int TFL = 64 * K;          // floats per tile
    constexpr int KIDX = K - 2;

    __shared__ float lds[4 * 4 * 640 + 4 * 55];  // 4 waves x 4 bufs x 640
    float* part = lds + 4 * 4 * 640;

    const int tid = threadIdx.x;
    const int lane = tid & 63;
    const int w = tid >> 6;
    float* buf = lds + w * 4 * 640;

    const int b = blockIdx.x >> 1;
    const int ch = blockIdx.x & 1;
    const float* Lw =
        L + ((size_t)b * TT + (size_t)ch * 2048 + (size_t)w * 512) * K;

    float acc[NACC];
#pragma unroll
    for (int i = 0; i < NACC; ++i) acc[i] = 0.f;

    // stage tile t into buffer (t&3)
    auto issue = [&](int t) {
        const float* src = Lw + (size_t)t * TFL;
        float* dst = buf + (t & 3) * 640;
#pragma unroll
        for (int s = 0; s < VF; ++s)
            gl_lds16(src + s * 256 + lane * 4, dst + s * 256);
        if constexpr (RL > 0)
            if (lane < RL) gl_lds16(src + VF * 256 + lane * 4, dst + VF * 256);
    };

    issue(0);
    issue(1);
    issue(2);

#pragma unroll
    for (int t = 0; t < 8; ++t) {
        if (t + 3 < 8) issue(t + 3);
        // wait until tile t has landed; keep younger tiles in flight.
        // imm: vmcnt=N (bits3:0), expcnt=7 (no wait), lgkmcnt=15 (no wait)
        if (t < 5)
            __builtin_amdgcn_s_waitcnt(0xF70 | (3 * VOPS));
        else if (t == 5)
            __builtin_amdgcn_s_waitcnt(0xF70 | (2 * VOPS));
        else if (t == 6)
            __builtin_amdgcn_s_waitcnt(0xF70 | (1 * VOPS));
        else
            __builtin_amdgcn_s_waitcnt(0xF70);
        __builtin_amdgcn_sched_barrier(0);

        const float* myrow = buf + (t & 3) * 640 + lane * K;
        float v[K];
#pragma unroll
        for (int c = 0; c < K; ++c) v[c] = myrow[c];
        row_update<K>(v, acc);
    }

    // Epilogue: wave shuffle-reduce, 4 wave-partials in LDS, write packed seg.
#pragma unroll
    for (int i = 0; i < NACC; ++i) {
        float x = acc[i];
#pragma unroll
        for (int off = 32; off > 0; off >>= 1) x += __shfl_down(x, off, 64);
        if (lane == 0) part[w * 55 + i] = x;
    }
    __syncthreads();

    if (tid < NACC) {
        const float x = part[0 * 55 + tid] + part[1 * 55 + tid] +
                        part[2 * 55 + tid] + part[3 * 55 + tid];
        int i = 0, rem = tid;
        while (rem >= K - i) { rem -= K - i; ++i; }
        const int j = i + rem;
        int tgt;  // diag-first layout within segment
        if (j == i) tgt = i;
        else tgt = K + i * (K - 1) - (i * (i - 1)) / 2 + (j - i - 1);
        float* gdst = ws + ((size_t)(b * 9 + KIDX) * 2 + ch) * 55;
        gdst[tgt] = x;  // unscaled; head applies 1/T
    }
}

// ---------------------------------------------------------------------------
// Kernel B: per batch row — gather partials, rank-sort segments, LayerNorm,
// MLP head. (identical to R4/R7, proven)
// ---------------------------------------------------------------------------
__device__ __forceinline__ float gelu_exact(float x) {
    return 0.5f * x * (1.0f + erff(x * 0.70710678118654752440f));
}

__global__ __launch_bounds__(256) void head_kernel(
    const float* __restrict__ ws, const float* __restrict__ gamma,
    const float* __restrict__ beta, const float* __restrict__ w1,
    const float* __restrict__ b1, const float* __restrict__ w2,
    const float* __restrict__ b2, const float* __restrict__ w3,
    const float* __restrict__ b3, float* __restrict__ out) {
    const int b = blockIdx.x;
    const int tid = threadIdx.x;

    __shared__ float pre[219];
    __shared__ float srt[219];
    __shared__ float xln[219];
    __shared__ float h1[256];
    __shared__ float h2[256];
    __shared__ float rs1[4], rs2[4];
    __shared__ float smu, srv;

    if (tid < 219) {
        int ik = 0;
        while (tid >= SEGF[ik + 1]) ++ik;
        const int local = tid - SEGF[ik];
        const float* p0 = ws + ((size_t)(b * 9 + ik) * 2) * 55;
        pre[tid] = (p0[local] + p0[55 + local]) * (1.0f / (float)TT);
    }
    __syncthreads();

    if (tid < 219) {
        int ik = 0;
        while (tid >= SEGF[ik + 1]) ++ik;
        const int K = ik + 2;
        const int base = SEGF[ik];
        const int local = tid - base;
        int sstart, slen, lidx;
        if (local < K) { sstart = base; slen = K; lidx = local; }
        else { sstart = base + K; slen = (K * (K - 1)) / 2; lidx = local - K; }
        const float v = pre[tid];
        int rank = 0;
        for (int m = 0; m < slen; ++m) {
            const float u = pre[sstart + m];
            rank += (u > v) || ((u == v) && (m < lidx));
        }
        srt[sstart + rank] = v;
    }
    __syncthreads();

    const float val = (tid < 219) ? srt[tid] : 0.f;
    float s1 = val, s2 = val * val;
#pragma unroll
    for (int off = 32; off > 0; off >>= 1) {
        s1 += __shfl_down(s1, off, 64);
        s2 += __shfl_down(s2, off, 64);
    }
    const int wave = tid >> 6, lane = tid & 63;
    if (lane == 0) { rs1[wave] = s1; rs2[wave] = s2; }
    __syncthreads();
    if (tid == 0) {
        const float t1 = rs1[0] + rs1[1] + rs1[2] + rs1[3];
        const float t2 = rs2[0] + rs2[1] + rs2[2] + rs2[3];
        const float mu = t1 * (1.0f / 219.0f);
        const float var = t2 * (1.0f / 219.0f) - mu * mu;
        smu = mu;
        srv = rsqrtf(var + 1e-5f);
    }
    __syncthreads();
    if (tid < 219) xln[tid] = (srt[tid] - smu) * srv * gamma[tid] + beta[tid];
    __syncthreads();

    {
        float a = b1[tid];
#pragma unroll 8
        for (int i = 0; i < 219; ++i) a = fmaf(xln[i], w1[i * 256 + tid], a);
        h1[tid] = gelu_exact(a);
    }
    __syncthreads();

    {
        float c = b2[tid];
#pragma unroll 8
        for (int i = 0; i < 256; ++i) c = fmaf(h1[i], w2[i * 256 + tid], c);
        h2[tid] = gelu_exact(c);
    }
    __syncthreads();

    if (tid < 9) {
        float o = b3[tid];
#pragma unroll 8
        for (int i = 0; i < 256; ++i) o = fmaf(h2[i], w3[i * 9 + tid], o);
        out[(size_t)b * 9 + tid] = o;
    }
}

// ---------------------------------------------------------------------------
extern "C" void kernel_launch(void* const* d_in, const int* in_sizes, int n_in,
                              void* d_out, int out_size, void* d_ws,
                              size_t ws_size, hipStream_t stream) {
    const float* l2 = (const float*)d_in[0];
    const float* l3 = (const float*)d_in[1];
    const float* l4 = (const float*)d_in[2];
    const float* l5 = (const float*)d_in[3];
    const float* l6 = (const float*)d_in[4];
    const float* l7 = (const float*)d_in[5];
    const float* l8 = (const float*)d_in[6];
    const float* l9 = (const float*)d_in[7];
    const float* l10 = (const float*)d_in[8];
    const float* gamma = (const float*)d_in[9];
    const float* beta = (const float*)d_in[10];
    const float* w1 = (const float*)d_in[11];
    const float* b1 = (const float*)d_in[12];
    const float* w2 = (const float*)d_in[13];
    const float* b2 = (const float*)d_in[14];
    const float* w3 = (const float*)d_in[15];
    const float* b3 = (const float*)d_in[16];

    float* wsf = (float*)d_ws;  // [256][9][2][55] floats
    float* outp = (float*)d_out;

    // heavy k first; per-k kernels give per-k profile attribution
    gk<10><<<512, 256, 0, stream>>>(l10, wsf);
    gk<9><<<512, 256, 0, stream>>>(l9, wsf);
    gk<8><<<512, 256, 0, stream>>>(l8, wsf);
    gk<7><<<512, 256, 0, stream>>>(l7, wsf);
    gk<6><<<512, 256, 0, stream>>>(l6, wsf);
    gk<5><<<512, 256, 0, stream>>>(l5, wsf);
    gk<4><<<512, 256, 0, stream>>>(l4, wsf);
    gk<3><<<512, 256, 0, stream>>>(l3, wsf);
    gk<2><<<512, 256, 0, stream>>>(l2, wsf);
    head_kernel<<<BB, 256, 0, stream>>>(wsf, gamma, beta, w1, b1, w2, b2, w3,
                                        b3, outp);
}